// Round 10
// baseline (41.314 us; speedup 1.0000x reference)
//
#include <hip/hip_runtime.h>
#include <math.h>

#define BB 32
#define II 512
#define OO 512
#define NN 16

#define NW 2            // n-window: the two nearest centers (lo = floor(nc))
#define LOMAX (NN - NW) // 14
#define CHI 16          // i's per block
#define QS (II / CHI)   // 32 -> grid = QS*OO = 16384 blocks
#define T1 128          // 2 waves/block; 16 blocks/CU resident

#if __has_builtin(__builtin_amdgcn_exp2f)
#define EXP2F(x) __builtin_amdgcn_exp2f(x)
#else
#define EXP2F(x) exp2f(x)
#endif
#if __has_builtin(__builtin_amdgcn_rcpf)
#define RCPF(x) __builtin_amdgcn_rcpf(x)
#else
#define RCPF(x) (1.0f / (x))
#endif

// KS = sqrt(log2 e): zs = z*KS so exp(-z^2) = exp2(-zs^2)
// K_A2N = (1/sqrt(2))/KS: u = alpha*z/sqrt(2) = (alpha*K_A2N)*zs
#define KS      1.2011224087f
#define K_A2N   0.5887050112f
// A&S 7.1.27: erf(x) = 1 - (1 + a1 x + a2 x^2 + a3 x^3 + a4 x^4)^-4, |err|<=5e-4
#define EA1 0.278393f
#define EA2 0.230389f
#define EA3 0.000972f
#define EA4 0.078108f

// Block = (q, o): bid = q*OO + o; q in [0,32). 128 threads = (b = tid&31) x
// (iw = tid>>5, 0..3). Each block: i in [q*16, q*16+16), one staging phase,
// one barrier, then 4 i x NW=2 elems per thread, per-b partials fused into
// out via atomicAdd (out zeroed by an in-graph memset node). 16384 small
// blocks / 16 resident per CU stagger the stage and compute phases across
// blocks (fixes the cohort-stall seen at 256-thread blocks).
// Window: two nearest centers; dropped terms at n-distance >= 1 -> z >= 3|s|
// -> added output error ~1e-4 worst case (measured absmax 2.4e-4 vs 1.2e-3).
// erf: A&S 7.1.27 poly (rcp-based); R8 showed the LUT-gather costs the same
// as the rcp it replaces, and the per-block LUT build (4.2M erff) is waste.
__global__ __launch_bounds__(T1, 8)
void kat_win(const float* __restrict__ x,
             const float* __restrict__ mx_train,
             const float* __restrict__ scale,
             const float* __restrict__ sigma,
             const float* __restrict__ alpha,
             const float* __restrict__ w,
             const float* __restrict__ mx_start,
             float* __restrict__ out)
{
    __shared__ float4 pr[CHI * NN];   // 4 KB  [i_loc][n] {c1s, c0s, a2n, w}
    __shared__ float  xs[BB * 17];    // 2.2 KB [b][ii], pitch 17 (odd -> conflict-free)
    __shared__ float2 sc[CHI];        // (inv_s15, -mxt*inv_s15)
    __shared__ float  red[4][BB];     // 0.5 KB

    const int bid = blockIdx.x;
    const int o   = bid & (OO - 1);
    const int q   = bid >> 9;
    const int tid = threadIdx.x;
    const int b   = tid & 31;
    const int iw  = tid >> 5;
    const int i0  = q * CHI;

    // ---- stage x[b][i0+ii] -> xs (coalesced 64B per 16 lanes) ----
#pragma unroll
    for (int p = 0; p < (BB * CHI) / T1; ++p) {     // 4 iters
        const int idx = p * T1 + tid;
        const int bb  = idx >> 4;
        const int ii  = idx & 15;
        xs[bb * 17 + ii] = x[bb * II + i0 + ii];
    }
    // ---- stage per-tuple constants (rcp amortized over 32 b) ----
#pragma unroll
    for (int p = 0; p < (CHI * NN) / T1; ++p) {     // 2 iters
        const int t  = p * T1 + tid;
        const int il = t >> 4;
        const int n  = t & 15;
        const int io = (i0 + il) * OO + o;
        const float sg  = fabsf(sigma[io * NN + n]) + 1e-8f;
        const float c1s = KS * RCPF(sg);
        const float ctr = fmaf(fabsf(scale[io]), mx_start[n], mx_train[io]);
        pr[il * NN + n] = make_float4(c1s, -ctr * c1s,
                                      alpha[io * NN + n] * K_A2N,
                                      w[io * NN + n]);
    }
    // ---- stage window coefs: nc = (x - mxt)*15/|s| ----
    if (tid < CHI) {
        const int io = (i0 + tid) * OO + o;
        const float s   = fmaxf(fabsf(scale[io]), 1e-20f);
        const float inv = 15.0f * RCPF(s);
        sc[tid] = make_float2(inv, -mx_train[io] * inv);
    }
    __syncthreads();

    // ---- compute: 4 i per thread, NW=2 window each ----
    float acc = 0.0f;
#pragma unroll
    for (int j = 0; j < CHI / 4; ++j) {
        const int ii = iw * 4 + j;
        const float  xv = xs[b * 17 + ii];
        const float2 s2 = sc[ii];
        const float  nc = fmaf(xv, s2.x, s2.y);
        const float lof = fminf(fmaxf(floorf(nc), 0.0f), (float)LOMAX);
        const int   lo  = (int)lof;
        const float4* pp = &pr[ii * NN + lo];
#pragma unroll
        for (int k = 0; k < NW; ++k) {
            const float4 P = pp[k];
            const float zs = fmaf(xv, P.x, P.y);     // z*sqrt(log2e)
            const float m  = -zs * zs;
            const float e  = EXP2F(m);               // exp(-z^2)
            const float u  = P.z * zs;               // alpha*z/sqrt(2)
            const float au = fabsf(u);
            float d = fmaf(EA4, au, EA3);
            d = fmaf(d, au, EA2);
            d = fmaf(d, au, EA1);
            d = fmaf(d, au, 1.0f);
            const float r  = RCPF(d);
            const float r2 = r * r;
            const float r4 = r2 * r2;
            const float erfu = __builtin_copysignf(1.0f - r4, u);
            const float gg   = fmaf(e, erfu, e);     // e*(1+erf(u))
            acc = fmaf(gg, P.w, acc);
        }
    }

    // ---- reduce over iw and fuse into out via atomics ----
    red[iw][b] = acc;
    __syncthreads();
    if (tid < BB) {
        const float s = red[0][tid] + red[1][tid] + red[2][tid] + red[3][tid];
        atomicAdd(&out[tid * OO + o], s);   // 16 writers per element
    }
}

extern "C" void kernel_launch(void* const* d_in, const int* in_sizes, int n_in,
                              void* d_out, int out_size, void* d_ws, size_t ws_size,
                              hipStream_t stream)
{
    const float* x        = (const float*)d_in[0];
    const float* mx_train = (const float*)d_in[1];
    const float* scale    = (const float*)d_in[2];
    const float* sigma    = (const float*)d_in[3];
    const float* alpha    = (const float*)d_in[4];
    const float* w        = (const float*)d_in[5];
    const float* mx_start = (const float*)d_in[6];
    float* out            = (float*)d_out;

    // zero the accumulator (graph-capturable memset node; float 0.0f == 0 bytes)
    hipMemsetAsync(d_out, 0, (size_t)out_size * sizeof(float), stream);
    kat_win<<<QS * OO, T1, 0, stream>>>(x, mx_train, scale, sigma,
                                        alpha, w, mx_start, out);
}

// Round 11
// 27.309 us; speedup vs baseline: 1.5128x; 1.5128x over previous
//
#include <hip/hip_runtime.h>
#include <math.h>

#define BB 32
#define II 512
#define OO 512
#define NN 16

#define NW 2            // n-window: the two nearest centers (lo = floor(nc))
#define LOMAX (NN - NW) // 14
#define QS 16           // i-split (partials in ws); grid = QS*OO = 8192 blocks
#define CHI 32          // i's per block (single chunk)

#if __has_builtin(__builtin_amdgcn_exp2f)
#define EXP2F(x) __builtin_amdgcn_exp2f(x)
#else
#define EXP2F(x) exp2f(x)
#endif
#if __has_builtin(__builtin_amdgcn_rcpf)
#define RCPF(x) __builtin_amdgcn_rcpf(x)
#else
#define RCPF(x) (1.0f / (x))
#endif

// KS = sqrt(log2 e): zs = z*KS so exp(-z^2) = exp2(-zs^2)
// K_A2N = (1/sqrt(2))/KS: u = alpha*z/sqrt(2) = (alpha*K_A2N)*zs
#define KS      1.2011224087f
#define K_A2N   0.5887050112f
// A&S 7.1.27: erf(x) = 1 - (1 + a1 x + a2 x^2 + a3 x^3 + a4 x^4)^-4, |err|<=5e-4
#define EA1 0.278393f
#define EA2 0.230389f
#define EA3 0.000972f
#define EA4 0.078108f

// R9's proven structure (27.4 us) with two isolated changes:
//  (1) poly erf body instead of LDS LUT -> kills the 8192x512 erff LUT
//      build (~4.2M library-erf calls) and 2 KB LDS. R8 showed LUT-gather
//      cost == rcp cost, so the body is speed-neutral.
//  (2) float2 param staging: tuples (2t, 2t+1) share an (i,o) row (n even)
//      -> sigma/alpha/w as aligned float2, 128 B/16-lane group, and one
//      scale/mx_train load per pair.
// NO atomics (R10's 32-writer device-scope atomicAdd regressed 14 us),
// NO geometry change (128-thr blocks doubled per-block fixed cost).
__global__ __launch_bounds__(256, 8)
void kat_win(const float* __restrict__ x,
             const float* __restrict__ mx_train,
             const float* __restrict__ scale,
             const float* __restrict__ sigma,
             const float* __restrict__ alpha,
             const float* __restrict__ w,
             const float* __restrict__ mx_start,
             float* __restrict__ ws)
{
    __shared__ float4 pr[CHI * NN];   // 8 KB  [i_loc][n] {c1s, c0s, a2n, w}
    __shared__ float  xs[BB * 33];    // 4.2 KB [b][ii], pitch 33 (2-way = free)
    __shared__ float2 sc[CHI];        // (inv_s15, -mxt*inv_s15)
    __shared__ float  red[8][BB];     // 1 KB

    const int bid = blockIdx.x;
    const int o   = bid & (OO - 1);
    const int q   = bid >> 9;
    const int tid = threadIdx.x;
    const int b   = tid & 31;
    const int iw  = tid >> 5;
    const int i0  = q * CHI;

    // ---- stage x[b][i0+ii] -> xs (coalesced) ----
#pragma unroll
    for (int p = 0; p < (BB * CHI) / 256; ++p) {
        const int idx = p * 256 + tid;
        const int bb  = idx >> 5;
        const int ii  = idx & 31;
        xs[bb * 33 + ii] = x[bb * II + i0 + ii];
    }
    // ---- stage per-tuple constants, 2 tuples/thread via float2 ----
    {
        const int t0 = tid * 2;              // tuple base, 0..510 (n0 even)
        const int il = t0 >> 4;
        const int n0 = t0 & 15;
        const int io = (i0 + il) * OO + o;
        const float2 sg2 = *reinterpret_cast<const float2*>(&sigma[io * NN + n0]);
        const float2 al2 = *reinterpret_cast<const float2*>(&alpha[io * NN + n0]);
        const float2 w2  = *reinterpret_cast<const float2*>(&w[io * NN + n0]);
        const float  sca = fabsf(scale[io]);
        const float  mxt = mx_train[io];
        const float  m0  = mx_start[n0];
        const float  m1  = mx_start[n0 + 1];

        const float c1s0 = KS * RCPF(fabsf(sg2.x) + 1e-8f);
        const float c1s1 = KS * RCPF(fabsf(sg2.y) + 1e-8f);
        const float ctr0 = fmaf(sca, m0, mxt);
        const float ctr1 = fmaf(sca, m1, mxt);
        pr[il * NN + n0]     = make_float4(c1s0, -ctr0 * c1s0, al2.x * K_A2N, w2.x);
        pr[il * NN + n0 + 1] = make_float4(c1s1, -ctr1 * c1s1, al2.y * K_A2N, w2.y);
    }
    // ---- stage window coefs: nc = (x - mxt)*15/|s| ----
    if (tid < CHI) {
        const int io = (i0 + tid) * OO + o;
        const float s   = fmaxf(fabsf(scale[io]), 1e-20f);
        const float inv = 15.0f * RCPF(s);
        sc[tid] = make_float2(inv, -mx_train[io] * inv);
    }
    __syncthreads();

    // ---- compute: 4 i per thread, NW=2 window each ----
    float acc = 0.0f;
#pragma unroll
    for (int j = 0; j < CHI / 8; ++j) {
        const int ii = iw + 8 * j;
        const float  xv = xs[b * 33 + ii];
        const float2 s2 = sc[ii];
        const float  nc = fmaf(xv, s2.x, s2.y);
        const float lof = fminf(fmaxf(floorf(nc), 0.0f), (float)LOMAX);
        const int   lo  = (int)lof;
        const float4* pp = &pr[ii * NN + lo];
#pragma unroll
        for (int k = 0; k < NW; ++k) {
            const float4 P = pp[k];
            const float zs = fmaf(xv, P.x, P.y);     // z*sqrt(log2e)
            const float m  = -zs * zs;
            const float e  = EXP2F(m);               // exp(-z^2)
            const float u  = P.z * zs;               // alpha*z/sqrt(2)
            const float au = fabsf(u);
            float d = fmaf(EA4, au, EA3);
            d = fmaf(d, au, EA2);
            d = fmaf(d, au, EA1);
            d = fmaf(d, au, 1.0f);
            const float r  = RCPF(d);
            const float r2 = r * r;
            const float r4 = r2 * r2;
            const float erfu = __builtin_copysignf(1.0f - r4, u);
            const float gg   = fmaf(e, erfu, e);     // e*(1+erf(u))
            acc = fmaf(gg, P.w, acc);
        }
    }

    // ---- reduce over iw (8 partials per b) ----
    red[iw][b] = acc;
    __syncthreads();
    if (tid < BB) {
        float s = 0.0f;
#pragma unroll
        for (int k = 0; k < 8; ++k) s += red[k][tid];
        ws[q * (BB * OO) + tid * OO + o] = s;   // ws[q][b][o]
    }
}

// out[b,o] = sum_q ws[q][b][o]; fully coalesced.
__global__ __launch_bounds__(256)
void kat_reduce(const float* __restrict__ ws, float* __restrict__ out)
{
    const int idx = blockIdx.x * 256 + threadIdx.x;
    if (idx < BB * OO) {
        float s = 0.0f;
#pragma unroll
        for (int qq = 0; qq < QS; ++qq) s += ws[qq * (BB * OO) + idx];
        out[idx] = s;
    }
}

extern "C" void kernel_launch(void* const* d_in, const int* in_sizes, int n_in,
                              void* d_out, int out_size, void* d_ws, size_t ws_size,
                              hipStream_t stream)
{
    const float* x        = (const float*)d_in[0];
    const float* mx_train = (const float*)d_in[1];
    const float* scale    = (const float*)d_in[2];
    const float* sigma    = (const float*)d_in[3];
    const float* alpha    = (const float*)d_in[4];
    const float* w        = (const float*)d_in[5];
    const float* mx_start = (const float*)d_in[6];
    float* ws             = (float*)d_ws;      // QS * B * O floats = 1 MB
    float* out            = (float*)d_out;

    kat_win<<<QS * OO, 256, 0, stream>>>(x, mx_train, scale, sigma,
                                         alpha, w, mx_start, ws);
    kat_reduce<<<(BB * OO + 255) / 256, 256, 0, stream>>>(ws, out);
}

// Round 12
// 22.171 us; speedup vs baseline: 1.8634x; 1.2317x over previous
//
#include <hip/hip_runtime.h>
#include <math.h>

#define BB 32
#define II 512
#define OO 512
#define NN 16

#define NW 2            // n-window: the two nearest centers (lo = floor(nc))
#define LOMAX (NN - NW) // 14
#define QS 16           // i-split (partials in ws); ws = QS*B*O floats = 1 MB
#define CHI 32          // i's per block
#define OPB 2           // o's per block -> 128 B contiguous param segments
#define NOB (OO / OPB)  // 256 o-blocks; grid = QS*NOB = 4096

#if __has_builtin(__builtin_amdgcn_exp2f)
#define EXP2F(x) __builtin_amdgcn_exp2f(x)
#else
#define EXP2F(x) exp2f(x)
#endif
#if __has_builtin(__builtin_amdgcn_rcpf)
#define RCPF(x) __builtin_amdgcn_rcpf(x)
#else
#define RCPF(x) (1.0f / (x))
#endif

// KS = sqrt(log2 e): zs = z*KS so exp(-z^2) = exp2(-zs^2)
// K_A2N = (1/sqrt(2))/KS: u = alpha*z/sqrt(2) = (alpha*K_A2N)*zs
#define KS      1.2011224087f
#define K_A2N   0.5887050112f
// A&S 7.1.27: erf(x) = 1 - (1 + a1 x + a2 x^2 + a3 x^3 + a4 x^4)^-4, |err|<=5e-4
#define EA1 0.278393f
#define EA2 0.230389f
#define EA3 0.000972f
#define EA4 0.078108f

// R11 + ONE change: o-pair blocks (OPB=2). Param rows for (i, o0) and
// (i, o0+1) are adjacent 64 B rows -> staging fetches 128 B contiguous
// segments via per-thread float4 (1 KB contiguous per wave instruction)
// instead of 64 B combs — attacks the param-fetch granularity wall
// identified after R11's neutral result. Body math, window (NW=2),
// QS=16 partials + separate reduce: unchanged (proven, absmax 2.44e-4).
__global__ __launch_bounds__(256, 8)
void kat_win(const float* __restrict__ x,
             const float* __restrict__ mx_train,
             const float* __restrict__ scale,
             const float* __restrict__ sigma,
             const float* __restrict__ alpha,
             const float* __restrict__ w,
             const float* __restrict__ mx_start,
             float* __restrict__ ws)
{
    __shared__ float4 pr[CHI * OPB * NN];  // 16 KB [i][op][n] {c1s,c0s,a2n,w}
    __shared__ float  xs[BB * 33];         // 4.2 KB [b][ii], pitch 33
    __shared__ float2 sc[CHI * OPB];       // 512 B (inv_s15, -mxt*inv_s15)
    __shared__ float  red[OPB][8][BB];     // 2 KB

    const int bid = blockIdx.x;
    const int ob  = bid & (NOB - 1);
    const int q   = bid >> 8;
    const int o0  = ob * OPB;
    const int tid = threadIdx.x;
    const int b   = tid & 31;
    const int iw  = tid >> 5;
    const int i0  = q * CHI;

    // ---- stage x[b][i0+ii] -> xs (coalesced) ----
#pragma unroll
    for (int p = 0; p < (BB * CHI) / 256; ++p) {
        const int idx = p * 256 + tid;
        const int bb  = idx >> 5;
        const int ii  = idx & 31;
        xs[bb * 33 + ii] = x[bb * II + i0 + ii];
    }
    // ---- stage per-tuple constants: float4 per thread, 128 B/segment ----
    {
        const int il = tid >> 3;             // 0..31
        const int r  = tid & 7;              // 0..7 -> 8 float4 = 128 B per il
        const int op = r >> 2;               // 0..1
        const int n0 = (r & 3) * 4;          // 0,4,8,12
        const int io = (i0 + il) * OO + o0 + op;
        const float4 sg4 = *reinterpret_cast<const float4*>(&sigma[io * NN + n0]);
        const float4 al4 = *reinterpret_cast<const float4*>(&alpha[io * NN + n0]);
        const float4 w4  = *reinterpret_cast<const float4*>(&w[io * NN + n0]);
        const float4 mx4 = *reinterpret_cast<const float4*>(&mx_start[n0]);
        const float  sca = fabsf(scale[io]);
        const float  mxt = mx_train[io];

        const float sg[4] = {sg4.x, sg4.y, sg4.z, sg4.w};
        const float al[4] = {al4.x, al4.y, al4.z, al4.w};
        const float wv[4] = {w4.x,  w4.y,  w4.z,  w4.w};
        const float mx[4] = {mx4.x, mx4.y, mx4.z, mx4.w};
        float4* dst = &pr[(il * OPB + op) * NN + n0];
#pragma unroll
        for (int c = 0; c < 4; ++c) {
            const float c1s = KS * RCPF(fabsf(sg[c]) + 1e-8f);
            const float ctr = fmaf(sca, mx[c], mxt);
            dst[c] = make_float4(c1s, -ctr * c1s, al[c] * K_A2N, wv[c]);
        }
    }
    // ---- stage window coefs: nc = (x - mxt)*15/|s| ----
    if (tid < CHI * OPB) {
        const int ii  = tid >> 1;
        const int op  = tid & 1;
        const int io  = (i0 + ii) * OO + o0 + op;
        const float s   = fmaxf(fabsf(scale[io]), 1e-20f);
        const float inv = 15.0f * RCPF(s);
        sc[tid] = make_float2(inv, -mx_train[io] * inv);
    }
    __syncthreads();

    // ---- compute: 4 i x 2 o per thread, NW=2 window each ----
    float acc0 = 0.0f, acc1 = 0.0f;
#pragma unroll
    for (int j = 0; j < CHI / 8; ++j) {
        const int ii = iw + 8 * j;
        const float xv = xs[b * 33 + ii];
#pragma unroll
        for (int op = 0; op < OPB; ++op) {
            const float2 s2 = sc[ii * OPB + op];
            const float  nc = fmaf(xv, s2.x, s2.y);
            const float lof = fminf(fmaxf(floorf(nc), 0.0f), (float)LOMAX);
            const int   lo  = (int)lof;
            const float4* pp = &pr[(ii * OPB + op) * NN + lo];
            float a = 0.0f;
#pragma unroll
            for (int k = 0; k < NW; ++k) {
                const float4 P = pp[k];
                const float zs = fmaf(xv, P.x, P.y);     // z*sqrt(log2e)
                const float m  = -zs * zs;
                const float e  = EXP2F(m);               // exp(-z^2)
                const float u  = P.z * zs;               // alpha*z/sqrt(2)
                const float au = fabsf(u);
                float d = fmaf(EA4, au, EA3);
                d = fmaf(d, au, EA2);
                d = fmaf(d, au, EA1);
                d = fmaf(d, au, 1.0f);
                const float r  = RCPF(d);
                const float r2 = r * r;
                const float r4 = r2 * r2;
                const float erfu = __builtin_copysignf(1.0f - r4, u);
                const float gg   = fmaf(e, erfu, e);     // e*(1+erf(u))
                a = fmaf(gg, P.w, a);
            }
            if (op == 0) acc0 += a; else acc1 += a;
        }
    }

    // ---- reduce over iw (8 partials per (op, b)) ----
    red[0][iw][b] = acc0;
    red[1][iw][b] = acc1;
    __syncthreads();
    if (tid < OPB * BB) {
        const int op = tid >> 5;
        const int bb = tid & 31;
        float s = 0.0f;
#pragma unroll
        for (int k = 0; k < 8; ++k) s += red[op][k][bb];
        ws[q * (BB * OO) + bb * OO + o0 + op] = s;   // ws[q][b][o]
    }
}

// out[b,o] = sum_q ws[q][b][o]; fully coalesced.
__global__ __launch_bounds__(256)
void kat_reduce(const float* __restrict__ ws, float* __restrict__ out)
{
    const int idx = blockIdx.x * 256 + threadIdx.x;
    if (idx < BB * OO) {
        float s = 0.0f;
#pragma unroll
        for (int qq = 0; qq < QS; ++qq) s += ws[qq * (BB * OO) + idx];
        out[idx] = s;
    }
}

extern "C" void kernel_launch(void* const* d_in, const int* in_sizes, int n_in,
                              void* d_out, int out_size, void* d_ws, size_t ws_size,
                              hipStream_t stream)
{
    const float* x        = (const float*)d_in[0];
    const float* mx_train = (const float*)d_in[1];
    const float* scale    = (const float*)d_in[2];
    const float* sigma    = (const float*)d_in[3];
    const float* alpha    = (const float*)d_in[4];
    const float* w        = (const float*)d_in[5];
    const float* mx_start = (const float*)d_in[6];
    float* ws             = (float*)d_ws;      // QS * B * O floats = 1 MB
    float* out            = (float*)d_out;

    kat_win<<<QS * NOB, 256, 0, stream>>>(x, mx_train, scale, sigma,
                                          alpha, w, mx_start, ws);
    kat_reduce<<<(BB * OO + 255) / 256, 256, 0, stream>>>(ws, out);
}